// Round 12
// baseline (504.097 us; speedup 1.0000x reference)
//
#include <hip/hip_runtime.h>
#include <stdint.h>

typedef _Float16 half2_t __attribute__((ext_vector_type(2)));
typedef short bf16x8 __attribute__((ext_vector_type(8)));
typedef float f32x4 __attribute__((ext_vector_type(4)));
typedef int i32x4 __attribute__((ext_vector_type(4)));
typedef int i32x8 __attribute__((ext_vector_type(8)));
typedef unsigned short u16;
typedef unsigned int u32;
typedef unsigned long long u64;

#define B_ 64
#define S_ 512
#define D_ 512
#define H_ 512
#define FF_ 1024
#define C_ 1000
#define V_ 32000

// scaling: W' = 128*Wh (fp4 e2m1), g = 256*h (fp8 e4m3, >=0).
#define SW4 128.0f
#define SH4 256.0f

__device__ __forceinline__ u16 f2bf(float f){
  u32 u = __builtin_bit_cast(u32, f);
  u = (u + 0x7FFFu + ((u >> 16) & 1u)) >> 16;
  return (u16)u;
}
__device__ __forceinline__ u32 pkbf(float a, float b){
  return (u32)f2bf(a) | ((u32)f2bf(b) << 16);
}
__device__ __forceinline__ u32 packh2(float a, float b){
  u16 lo = __builtin_bit_cast(u16, (_Float16)a);
  u16 hi = __builtin_bit_cast(u16, (_Float16)b);
  return (u32)lo | ((u32)hi << 16);
}
__device__ __forceinline__ float fdot2u(u32 a, u32 b, float c){
  return __builtin_amdgcn_fdot2(__builtin_bit_cast(half2_t, a),
                                __builtin_bit_cast(half2_t, b), c, false);
}
__device__ __forceinline__ float h2f(u16 h){
  return (float)__builtin_bit_cast(_Float16, h);
}

// ---- P: Wx transpose+cvt [0,64) | Wh fp4 fragments [64,96) ----
__global__ void k_prep(const float* __restrict__ Wx, u16* __restrict__ WxT,
                       const float* __restrict__ Wh, uint4* __restrict__ Wf4){
  __shared__ u16 t[64][65];
  int bid = blockIdx.x, tid = threadIdx.x;
  if (bid < 64){
    int bx = bid & 7, by = bid >> 3;
    int c = tid & 63, r0 = (tid >> 6) * 16;
    #pragma unroll
    for (int i = 0; i < 16; i++){
      int k = by * 64 + r0 + i, n = bx * 64 + c;
      t[r0 + i][c] = f2bf(Wx[k * 512 + n]);
    }
    __syncthreads();
    #pragma unroll
    for (int i = 0; i < 16; i++){
      int n = bx * 64 + r0 + i, k = by * 64 + c;
      WxT[n * 512 + k] = t[c][r0 + i];
    }
  } else {
    int g = (bid - 64) * 256 + tid;            // 8192
    int fidx = g >> 6, l = g & 63;
    int wv = fidx >> 4, ct = (fidx >> 2) & 3, kt = fidx & 3;
    int q = l >> 4, n = wv * 64 + ct * 16 + (l & 15);
    int k0 = kt * 128 + q * 32;
    u32 d[4] = {0u, 0u, 0u, 0u};
    #pragma unroll
    for (int j = 0; j < 32; j++){
      float w = Wh[(size_t)(k0 + j) * 512 + n] * SW4;
      float aw = fabsf(w);
      u32 s = (w < 0.f) ? 8u : 0u;
      u32 c;
      if (aw < 2.f) c = (u32)(int)rintf(aw * 2.f);
      else if (aw < 4.f) c = 4u + (u32)(int)rintf(aw - 2.f);
      else { c = 6u + (u32)(int)rintf((aw - 4.f) * 0.5f); if (c > 7u) c = 7u; }
      d[j >> 3] |= (c | s) << (4 * (j & 7));
    }
    uint4 o; o.x = d[0]; o.y = d[1]; o.z = d[2]; o.w = d[3];
    Wf4[(size_t)fidx * 64 + l] = o;
  }
}

// ---- G: vocab GEMM [0,500) + weight packs [500,3060) + sync-zero ----
__global__ __launch_bounds__(512) void k_gemm(const float* __restrict__ emb,
                                              const u16* __restrict__ WxT,
                                              const float* __restrict__ bias,
                                              u16* __restrict__ xpV,
                                              const float* __restrict__ W1, u32* __restrict__ W1p,
                                              const float* __restrict__ W2, u32* __restrict__ W2p,
                                              const float* __restrict__ Wo, u32* __restrict__ Wop,
                                              u32* __restrict__ sync){
  __shared__ __align__(16) u16 As[64 * 40];
  int bid = blockIdx.x, tid = threadIdx.x;
  if (bid >= 500){
    if (bid == 500 && tid < 8) sync[tid] = 0;  // re-arm tailm barriers each call
    if (bid < 1012){
      int i = (bid - 500) * 512 + tid;         // 262144 = 256p x 1024n
      int p = i >> 10, n = i & 1023;
      W1p[p * FF_ + n] = packh2(W1[(2 * p) * FF_ + n], W1[(2 * p + 1) * FF_ + n]);
    } else if (bid < 2036){
      int i = (bid - 1012) * 512 + tid;        // 524288 = 512p x 1024n
      int p = i >> 10, n = i & 1023;
      W2p[p * FF_ + n] = packh2(W2[(2 * p) * FF_ + n], W2[(2 * p + 1) * FF_ + n]);
    } else {
      int i = (bid - 2036) * 512 + tid;        // 512p x 1024 (n<1000 valid)
      int p = i >> 10, n = i & 1023;
      if (n < C_)
        Wop[p * C_ + n] = packh2(Wo[(2 * p) * C_ + n], Wo[(2 * p + 1) * C_ + n]);
    }
    return;
  }
  int m0 = bid * 64;
  int w = tid >> 6, l = tid & 63, kg = l >> 4, r16 = l & 15;
  const u16* bptr[4];
  #pragma unroll
  for (int ni = 0; ni < 4; ni++)
    bptr[ni] = WxT + (size_t)(w * 64 + ni * 16 + r16) * 512 + kg * 8;
  f32x4 acc[4][4];
  #pragma unroll
  for (int mi = 0; mi < 4; mi++)
    #pragma unroll
    for (int ni = 0; ni < 4; ni++) acc[mi][ni] = (f32x4){0.f, 0.f, 0.f, 0.f};
  int srow = tid >> 3, sk = (tid & 7) * 4;
  const float* ebase = emb + (size_t)(m0 + srow) * 512 + sk;
  float4 f = *(const float4*)ebase;            // kt = 0
  for (int kt = 0; kt < 16; kt++){
    u32 lo = pkbf(f.x, f.y), hi = pkbf(f.z, f.w);
    float4 fn;
    if (kt < 15) fn = *(const float4*)(ebase + (kt + 1) * 32);   // prefetch
    __syncthreads();
    uint2 st; st.x = lo; st.y = hi;
    *(uint2*)(As + srow * 40 + sk) = st;
    __syncthreads();
    bf16x8 bfr[4], af[4];
    #pragma unroll
    for (int ni = 0; ni < 4; ni++)
      bfr[ni] = *(const bf16x8*)(bptr[ni] + kt * 32);
    #pragma unroll
    for (int mi = 0; mi < 4; mi++)
      af[mi] = *(const bf16x8*)(As + (mi * 16 + r16) * 40 + kg * 8);
    #pragma unroll
    for (int mi = 0; mi < 4; mi++)
      #pragma unroll
      for (int ni = 0; ni < 4; ni++)
        acc[mi][ni] = __builtin_amdgcn_mfma_f32_16x16x32_bf16(af[mi], bfr[ni], acc[mi][ni], 0, 0, 0);
    f = fn;
  }
  #pragma unroll
  for (int ni = 0; ni < 4; ni++){
    int col = w * 64 + ni * 16 + r16;
    float bb = bias[col];
    #pragma unroll
    for (int mi = 0; mi < 4; mi++){
      int mb = m0 + mi * 16 + kg * 4;
      #pragma unroll
      for (int r = 0; r < 4; r++){
        float v = (acc[mi][ni][r] + bb) * SH4;
        xpV[(size_t)(mb + r) * 512 + col] = __builtin_bit_cast(u16, (_Float16)v);
      }
    }
  }
}

// ---- R v3: scan with A=fp8 g (cbsz=0), B=fp4 weights (blgp=4). ----
// g = one fp8 byte per column (512 B, double-buffered). Epilogue: single
// cvt_pk_fp8 + own-byte ds_write (no shfl, no encode chain).
__global__ __launch_bounds__(512, 2) void k_rnn(
    const uint4* __restrict__ Wf4, const u16* __restrict__ xpV,
    const int* __restrict__ tokens, u32* __restrict__ hpack){
  __shared__ __align__(32) unsigned char gA[512];
  __shared__ __align__(32) unsigned char gB[512];
  __shared__ int toks[512];
  int b = blockIdx.x, tid = threadIdx.x;
  int wv = tid >> 6, l = tid & 63, q = l >> 4, n16 = l & 15;
  int col = wv * 64 + q * 16 + n16;

  i32x8 wgt[16];
  #pragma unroll
  for (int ct = 0; ct < 4; ct++)
    #pragma unroll
    for (int kt = 0; kt < 4; kt++){
      int fidx = (wv * 4 + ct) * 4 + kt;
      uint4 wl = Wf4[(size_t)fidx * 64 + l];
      i32x8 w8 = {(int)wl.x, (int)wl.y, (int)wl.z, (int)wl.w, 0, 0, 0, 0};
      wgt[ct * 4 + kt] = w8;
    }

  toks[tid] = tokens[b * 512 + tid];
  if (tid < 128) ((u32*)gA)[tid] = 0;
  __syncthreads();

  const u16* xpc = xpV + col;
  u16 xraw = xpc[(size_t)toks[0] * 512];
  u32 greg = 0;

#define RNN_STEP(T, SRC, DST)                                                 \
  {                                                                           \
    int tn = toks[(T + 1) & 511];                                             \
    u16 xnext = xpc[(size_t)tn * 512];                                        \
    bool wr = toks[T] != 0;                                                   \
    i32x8 a80 = *(const i32x8*)(SRC + 0 * 128 + q * 32);                      \
    i32x8 a81 = *(const i32x8*)(SRC + 1 * 128 + q * 32);                      \
    i32x8 a82 = *(const i32x8*)(SRC + 2 * 128 + q * 32);                      \
    i32x8 a83 = *(const i32x8*)(SRC + 3 * 128 + q * 32);                      \
    f32x4 acc0 = {0.f,0.f,0.f,0.f}, acc1 = {0.f,0.f,0.f,0.f};                 \
    f32x4 acc2 = {0.f,0.f,0.f,0.f}, acc3 = {0.f,0.f,0.f,0.f};                 \
    __builtin_amdgcn_s_setprio(1);                                            \
    acc0 = __builtin_amdgcn_mfma_scale_f32_16x16x128_f8f6f4(a80, wgt[0],  acc0, 0, 4, 0, 127, 0, 127); \
    acc1 = __builtin_amdgcn_mfma_scale_f32_16x16x128_f8f6f4(a80, wgt[4],  acc1, 0, 4, 0, 127, 0, 127); \
    acc2 = __builtin_amdgcn_mfma_scale_f32_16x16x128_f8f6f4(a80, wgt[8],  acc2, 0, 4, 0, 127, 0, 127); \
    acc3 = __builtin_amdgcn_mfma_scale_f32_16x16x128_f8f6f4(a80, wgt[12], acc3, 0, 4, 0, 127, 0, 127); \
    acc0 = __builtin_amdgcn_mfma_scale_f32_16x16x128_f8f6f4(a81, wgt[1],  acc0, 0, 4, 0, 127, 0, 127); \
    acc1 = __builtin_amdgcn_mfma_scale_f32_16x16x128_f8f6f4(a81, wgt[5],  acc1, 0, 4, 0, 127, 0, 127); \
    acc2 = __builtin_amdgcn_mfma_scale_f32_16x16x128_f8f6f4(a81, wgt[9],  acc2, 0, 4, 0, 127, 0, 127); \
    acc3 = __builtin_amdgcn_mfma_scale_f32_16x16x128_f8f6f4(a81, wgt[13], acc3, 0, 4, 0, 127, 0, 127); \
    acc0 = __builtin_amdgcn_mfma_scale_f32_16x16x128_f8f6f4(a82, wgt[2],  acc0, 0, 4, 0, 127, 0, 127); \
    acc1 = __builtin_amdgcn_mfma_scale_f32_16x16x128_f8f6f4(a82, wgt[6],  acc1, 0, 4, 0, 127, 0, 127); \
    acc2 = __builtin_amdgcn_mfma_scale_f32_16x16x128_f8f6f4(a82, wgt[10], acc2, 0, 4, 0, 127, 0, 127); \
    acc3 = __builtin_amdgcn_mfma_scale_f32_16x16x128_f8f6f4(a82, wgt[14], acc3, 0, 4, 0, 127, 0, 127); \
    acc0 = __builtin_amdgcn_mfma_scale_f32_16x16x128_f8f6f4(a83, wgt[3],  acc0, 0, 4, 0, 127, 0, 127); \
    acc1 = __builtin_amdgcn_mfma_scale_f32_16x16x128_f8f6f4(a83, wgt[7],  acc1, 0, 4, 0, 127, 0, 127); \
    acc2 = __builtin_amdgcn_mfma_scale_f32_16x16x128_f8f6f4(a83, wgt[11], acc2, 0, 4, 0, 127, 0, 127); \
    acc3 = __builtin_amdgcn_mfma_scale_f32_16x16x128_f8f6f4(a83, wgt[15], acc3, 0, 4, 0, 127, 0, 127); \
    __builtin_amdgcn_s_setprio(0);                                            \
    float av = (q == 0) ? acc0[0] : (q == 1) ? acc1[0] : (q == 2) ? acc2[0] : acc3[0]; \
    float gn = fmaxf(fmaf(av, 1.0f / SW4, h2f(xraw)), 0.f);                   \
    u32 pk = __builtin_amdgcn_cvt_pk_fp8_f32(gn, gn, 0, false) & 0xFFu;       \
    if (wr) greg = pk;                                                        \
    DST[col] = (unsigned char)greg;                                           \
    xraw = xnext;                                                             \
  }

  #pragma unroll 1
  for (int t = 0; t < 512; t += 2){
    RNN_STEP(t, gA, gB);
    __syncthreads();
    RNN_STEP(t + 1, gB, gA);
    __syncthreads();
  }
#undef RNN_STEP

  if (tid < 256){
    u32 two = *(const u16*)(gA + 2 * tid);
    float f0 = __builtin_amdgcn_cvt_f32_fp8(two, 0) * (1.0f / SH4);
    float f1 = __builtin_amdgcn_cvt_f32_fp8(two, 1) * (1.0f / SH4);
    hpack[b * 256 + tid] = packh2(f0, f1);
  }
}

// ---- grid-wide barrier (all blocks co-resident; counters pre-zeroed) ----
__device__ __forceinline__ void gridbar(u32* cnt, u32 target){
  __threadfence();
  __syncthreads();
  if (threadIdx.x == 0){
    atomicAdd(cnt, 1u);
    while (atomicAdd(cnt, 0u) < target) __builtin_amdgcn_s_sleep(2);
  }
  __syncthreads();
  __threadfence();
}

// ---- T: merged fc1+fc2+outz+norm. 128 blocks x 256 thr (co-resident). ----
__global__ __launch_bounds__(256, 1) void k_tailm(const u32* __restrict__ hpack,
    const u32* __restrict__ W1p, const float* __restrict__ b1,
    const u32* __restrict__ W2p, const float* __restrict__ b2,
    const u32* __restrict__ Wop, const float* __restrict__ bo,
    u32* __restrict__ y1p, u32* __restrict__ y2p,
    float* __restrict__ zbuf, float* __restrict__ out, u32* __restrict__ sync){
  __shared__ u32 h0[512], h1[512];
  __shared__ float redm[4], reds[4];
  int bid = blockIdx.x, tid = threadIdx.x;
  int nx = bid & 3, bp = bid >> 2;
  int ba = bp * 2, bb = ba + 1;

  // phase 1: fc1  (n-slice nx, batches ba/bb)
  {
    h0[tid] = hpack[ba * 256 + tid];
    h1[tid] = hpack[bb * 256 + tid];
    __syncthreads();
    int n = nx * 256 + tid;
    float a0 = 0.f, a1 = 0.f;
    #pragma unroll 8
    for (int p = 0; p < 256; p++){
      u32 w = W1p[p * FF_ + n];
      a0 = fdot2u(w, h0[p], a0);
      a1 = fdot2u(w, h1[p], a1);
    }
    float bbv = b1[n];
    float y0 = fmaxf(a0 + bbv, 0.f), y1 = fmaxf(a1 + bbv, 0.f);
    float o0 = __shfl_xor(y0, 1), o1 = __shfl_xor(y1, 1);
    if (!(tid & 1)){
      y1p[ba * 512 + (n >> 1)] = packh2(y0, o0);
      y1p[bb * 512 + (n >> 1)] = packh2(y1, o1);
    }
  }
  gridbar(sync + 0, 128);

  // phase 2: fc2
  {
    h0[tid] = y1p[ba * 512 + tid];       h1[tid] = y1p[bb * 512 + tid];
    h0[tid + 256] = y1p[ba * 512 + 256 + tid];
    h1[tid + 256] = y1p[bb * 512 + 256 + tid];
    __syncthreads();
    int n = nx * 256 + tid;
    float a0 = 0.f, a1 = 0.f;
    #pragma unroll 8
    for (int p = 0; p < 512; p++){
      u32 w = W2p[p * FF_ + n];
      a0 = fdot2u(w, h0[p], a0);
      a1 = fdot2u(w, h1[p], a1);
    }
    float bbv = b2[n];
    float y0 = fmaxf(a0 + bbv, 0.f), y1 = fmaxf(a1 + bbv, 0.f);
    float o0 = __shfl_xor(y0, 1), o1 = __shfl_xor(y1, 1);
    if (!(tid & 1)){
      y2p[ba * 512 + (n >> 1)] = packh2(y0, o0);
      y2p[bb * 512 + (n >> 1)] = packh2(y1, o1);
    }
  }
  gridbar(sync + 1, 128);

  // phase 3: outz (c-slice nx*250)
  {
    h0[tid] = y2p[ba * 512 + tid];       h1[tid] = y2p[bb * 512 + tid];
    h0[tid + 256] = y2p[ba * 512 + 256 + tid];
    h1[tid + 256] = y2p[bb * 512 + 256 + tid];
    __syncthreads();
    if (tid < 250){
      int n = nx * 250 + tid;
      float a0 = 0.f, a1 = 0.f;
      #pragma unroll 8
      for (int p = 0; p < 512; p++){
        u32 w = Wop[p * C_ + n];
        a0 = fdot2u(w, h0[p], a0);
        a1 = fdot2u(w, h1[p], a1);
      }
      float bbv = bo[n];
      zbuf[ba * C_ + n] = a0 + bbv;
      zbuf[bb * C_ + n] = a1 + bbv;
    }
  }
  gridbar(sync + 2, 128);

  // phase 4: softmax normalize (first 64 blocks; b = bid)
  if (bid < 64){
    int b = bid;
    float z0 = zbuf[b * C_ + tid];
    float z1 = zbuf[b * C_ + 256 + tid];
    float z2 = zbuf[b * C_ + 512 + tid];
    bool v3 = (768 + tid) < C_;
    float z3 = v3 ? zbuf[b * C_ + 768 + tid] : -1e30f;
    float mx = fmaxf(fmaxf(z0, z1), fmaxf(z2, z3));
    #pragma unroll
    for (int o = 1; o < 64; o <<= 1) mx = fmaxf(mx, __shfl_xor(mx, o));
    if ((tid & 63) == 0) redm[tid >> 6] = mx;
    __syncthreads();
    mx = fmaxf(fmaxf(redm[0], redm[1]), fmaxf(redm[2], redm[3]));
    float e0 = __expf(z0 - mx), e1 = __expf(z1 - mx), e2 = __expf(z2 - mx);
    float e3 = v3 ? __expf(z3 - mx) : 0.f;
    float s = e0 + e1 + e2 + e3;
    #pragma unroll
    for (int o = 1; o < 64; o <<= 1) s += __shfl_xor(s, o);
    if ((tid & 63) == 0) reds[tid >> 6] = s;
    __syncthreads();
    s = reds[0] + reds[1] + reds[2] + reds[3];
    float inv = 1.0f / s;
    out[b * C_ + tid] = e0 * inv;
    out[b * C_ + 256 + tid] = e1 * inv;
    out[b * C_ + 512 + tid] = e2 * inv;
    if (v3) out[b * C_ + 768 + tid] = e3 * inv;
  }
}

extern "C" void kernel_launch(void* const* d_in, const int* in_sizes, int n_in,
                              void* d_out, int out_size, void* d_ws, size_t ws_size,
                              hipStream_t stream) {
  const int*   tokens = (const int*)d_in[0];
  const float* emb    = (const float*)d_in[1];
  const float* Wx     = (const float*)d_in[2];
  const float* Wh     = (const float*)d_in[3];
  const float* brnn   = (const float*)d_in[4];
  const float* W1     = (const float*)d_in[5];
  const float* b1     = (const float*)d_in[6];
  const float* W2     = (const float*)d_in[7];
  const float* b2     = (const float*)d_in[8];
  const float* Wo     = (const float*)d_in[9];
  const float* bo     = (const float*)d_in[10];
  float* out = (float*)d_out;

  char* ws = (char*)d_ws;
  size_t off = 0;
  auto alloc = [&](size_t bytes) -> void* {
    void* p = ws + off;
    off += (bytes + 255) & ~(size_t)255;
    return p;
  };
  u16* WxT    = (u16*)alloc((size_t)512 * 512 * 2);
  u16* xpV    = (u16*)alloc((size_t)V_ * 512 * 2);
  uint4* Wf4  = (uint4*)alloc((size_t)128 * 64 * 16);
  u32* W1p    = (u32*)alloc((size_t)256 * 1024 * 4);
  u32* W2p    = (u32*)alloc((size_t)512 * 1024 * 4);
  u32* Wop    = (u32*)alloc((size_t)512 * 1000 * 4);
  u32* hpack  = (u32*)alloc((size_t)64 * 256 * 4);
  u32* y1p    = (u32*)alloc((size_t)64 * 512 * 4);
  u32* y2p    = (u32*)alloc((size_t)64 * 512 * 4);
  float* zbuf = (float*)alloc((size_t)64 * 1000 * 4);
  u32* sync   = (u32*)alloc(256);

  k_prep<<<dim3(96), dim3(256), 0, stream>>>(Wx, WxT, Wh, Wf4);
  k_gemm<<<dim3(3060), dim3(512), 0, stream>>>(emb, WxT, brnn, xpV,
                                               W1, W1p, W2, W2p, Wo, Wop, sync);
  k_rnn<<<dim3(64), dim3(512), 0, stream>>>(Wf4, xpV, tokens, hpack);
  k_tailm<<<dim3(128), dim3(256), 0, stream>>>(hpack, W1p, b1, W2p, b2, Wop, bo,
                                               y1p, y2p, zbuf, out, sync);
}

// Round 13
// 421.871 us; speedup vs baseline: 1.1949x; 1.1949x over previous
//
#include <hip/hip_runtime.h>
#include <stdint.h>

typedef _Float16 half2_t __attribute__((ext_vector_type(2)));
typedef short bf16x8 __attribute__((ext_vector_type(8)));
typedef float f32x4 __attribute__((ext_vector_type(4)));
typedef int i32x4 __attribute__((ext_vector_type(4)));
typedef int i32x8 __attribute__((ext_vector_type(8)));
typedef unsigned short u16;
typedef unsigned int u32;
typedef unsigned long long u64;

#define B_ 64
#define S_ 512
#define D_ 512
#define H_ 512
#define FF_ 1024
#define C_ 1000
#define V_ 32000

// scaling: W' = 128*Wh (fp4 e2m1), g = 256*h (fp4, >=0).
#define SW4 128.0f
#define SH4 256.0f

__device__ __forceinline__ u16 f2bf(float f){
  u32 u = __builtin_bit_cast(u32, f);
  u = (u + 0x7FFFu + ((u >> 16) & 1u)) >> 16;
  return (u16)u;
}
__device__ __forceinline__ u32 pkbf(float a, float b){
  return (u32)f2bf(a) | ((u32)f2bf(b) << 16);
}
__device__ __forceinline__ u32 packh2(float a, float b){
  u16 lo = __builtin_bit_cast(u16, (_Float16)a);
  u16 hi = __builtin_bit_cast(u16, (_Float16)b);
  return (u32)lo | ((u32)hi << 16);
}
__device__ __forceinline__ float fdot2u(u32 a, u32 b, float c){
  return __builtin_amdgcn_fdot2(__builtin_bit_cast(half2_t, a),
                                __builtin_bit_cast(half2_t, b), c, false);
}
__device__ __forceinline__ float h2f(u16 h){
  return (float)__builtin_bit_cast(_Float16, h);
}
__device__ __forceinline__ float fp4val(u32 c){
  int e = (c >> 1) & 3;
  float m = 1.0f + 0.5f * (float)(c & 1);
  return (e == 0) ? 0.5f * (float)(c & 1) : m * (float)(1 << (e - 1));
}

// ---- P: Wx transpose+cvt [0,64) | Wh fp4 fragments [64,96) ----
__global__ void k_prep(const float* __restrict__ Wx, u16* __restrict__ WxT,
                       const float* __restrict__ Wh, uint4* __restrict__ Wf4){
  __shared__ u16 t[64][65];
  int bid = blockIdx.x, tid = threadIdx.x;
  if (bid < 64){
    int bx = bid & 7, by = bid >> 3;
    int c = tid & 63, r0 = (tid >> 6) * 16;
    #pragma unroll
    for (int i = 0; i < 16; i++){
      int k = by * 64 + r0 + i, n = bx * 64 + c;
      t[r0 + i][c] = f2bf(Wx[k * 512 + n]);
    }
    __syncthreads();
    #pragma unroll
    for (int i = 0; i < 16; i++){
      int n = bx * 64 + r0 + i, k = by * 64 + c;
      WxT[n * 512 + k] = t[c][r0 + i];
    }
  } else {
    int g = (bid - 64) * 256 + tid;            // 8192
    int fidx = g >> 6, l = g & 63;
    int wv = fidx >> 4, ct = (fidx >> 2) & 3, kt = fidx & 3;
    int q = l >> 4, n = wv * 64 + ct * 16 + (l & 15);
    int k0 = kt * 128 + q * 32;
    u32 d[4] = {0u, 0u, 0u, 0u};
    #pragma unroll
    for (int j = 0; j < 32; j++){
      float w = Wh[(size_t)(k0 + j) * 512 + n] * SW4;
      float aw = fabsf(w);
      u32 s = (w < 0.f) ? 8u : 0u;
      u32 c;
      if (aw < 2.f) c = (u32)(int)rintf(aw * 2.f);
      else if (aw < 4.f) c = 4u + (u32)(int)rintf(aw - 2.f);
      else { c = 6u + (u32)(int)rintf((aw - 4.f) * 0.5f); if (c > 7u) c = 7u; }
      d[j >> 3] |= (c | s) << (4 * (j & 7));
    }
    uint4 o; o.x = d[0]; o.y = d[1]; o.z = d[2]; o.w = d[3];
    Wf4[(size_t)fidx * 64 + l] = o;
  }
}

// ---- G: vocab GEMM [0,500) + weight packs [500,3060) + counter re-arm ----
__global__ __launch_bounds__(512) void k_gemm(const float* __restrict__ emb,
                                              const u16* __restrict__ WxT,
                                              const float* __restrict__ bias,
                                              u16* __restrict__ xpV,
                                              const float* __restrict__ W1, u32* __restrict__ W1p,
                                              const float* __restrict__ W2, u32* __restrict__ W2p,
                                              const float* __restrict__ Wo, u32* __restrict__ Wop,
                                              u32* __restrict__ sync){
  __shared__ __align__(16) u16 As[64 * 40];
  int bid = blockIdx.x, tid = threadIdx.x;
  if (bid >= 500){
    if (bid == 500 && tid < 128) sync[tid] = 0;  // re-arm tail counters each call
    if (bid < 1012){
      int i = (bid - 500) * 512 + tid;         // 262144 = 256p x 1024n
      int p = i >> 10, n = i & 1023;
      W1p[p * FF_ + n] = packh2(W1[(2 * p) * FF_ + n], W1[(2 * p + 1) * FF_ + n]);
    } else if (bid < 2036){
      int i = (bid - 1012) * 512 + tid;        // 524288 = 512p x 1024n
      int p = i >> 10, n = i & 1023;
      W2p[p * FF_ + n] = packh2(W2[(2 * p) * FF_ + n], W2[(2 * p + 1) * FF_ + n]);
    } else {
      int i = (bid - 2036) * 512 + tid;        // 512p x 1024 (n<1000 valid)
      int p = i >> 10, n = i & 1023;
      if (n < C_)
        Wop[p * C_ + n] = packh2(Wo[(2 * p) * C_ + n], Wo[(2 * p + 1) * C_ + n]);
    }
    return;
  }
  int m0 = bid * 64;
  int w = tid >> 6, l = tid & 63, kg = l >> 4, r16 = l & 15;
  const u16* bptr[4];
  #pragma unroll
  for (int ni = 0; ni < 4; ni++)
    bptr[ni] = WxT + (size_t)(w * 64 + ni * 16 + r16) * 512 + kg * 8;
  f32x4 acc[4][4];
  #pragma unroll
  for (int mi = 0; mi < 4; mi++)
    #pragma unroll
    for (int ni = 0; ni < 4; ni++) acc[mi][ni] = (f32x4){0.f, 0.f, 0.f, 0.f};
  int srow = tid >> 3, sk = (tid & 7) * 4;
  const float* ebase = emb + (size_t)(m0 + srow) * 512 + sk;
  float4 f = *(const float4*)ebase;            // kt = 0
  for (int kt = 0; kt < 16; kt++){
    u32 lo = pkbf(f.x, f.y), hi = pkbf(f.z, f.w);
    float4 fn;
    if (kt < 15) fn = *(const float4*)(ebase + (kt + 1) * 32);   // prefetch
    __syncthreads();
    uint2 st; st.x = lo; st.y = hi;
    *(uint2*)(As + srow * 40 + sk) = st;
    __syncthreads();
    bf16x8 bfr[4], af[4];
    #pragma unroll
    for (int ni = 0; ni < 4; ni++)
      bfr[ni] = *(const bf16x8*)(bptr[ni] + kt * 32);
    #pragma unroll
    for (int mi = 0; mi < 4; mi++)
      af[mi] = *(const bf16x8*)(As + (mi * 16 + r16) * 40 + kg * 8);
    #pragma unroll
    for (int mi = 0; mi < 4; mi++)
      #pragma unroll
      for (int ni = 0; ni < 4; ni++)
        acc[mi][ni] = __builtin_amdgcn_mfma_f32_16x16x32_bf16(af[mi], bfr[ni], acc[mi][ni], 0, 0, 0);
    f = fn;
  }
  #pragma unroll
  for (int ni = 0; ni < 4; ni++){
    int col = w * 64 + ni * 16 + r16;
    float bb = bias[col];
    #pragma unroll
    for (int mi = 0; mi < 4; mi++){
      int mb = m0 + mi * 16 + kg * 4;
      #pragma unroll
      for (int r = 0; r < 4; r++){
        float v = (acc[mi][ni][r] + bb) * SH4;
        xpV[(size_t)(mb + r) * 512 + col] = __builtin_bit_cast(u16, (_Float16)v);
      }
    }
  }
}

// ---- R: 512-step RNN scan via MX-fp4 MFMA (K=128). R11 version (control). ----
__global__ __launch_bounds__(512, 2) void k_rnn(
    const uint4* __restrict__ Wf4, const u16* __restrict__ xpV,
    const int* __restrict__ tokens, u32* __restrict__ hpack){
  __shared__ __align__(16) unsigned char gA[256];
  __shared__ __align__(16) unsigned char gB[256];
  __shared__ int toks[512];
  int b = blockIdx.x, tid = threadIdx.x;
  int wv = tid >> 6, l = tid & 63, q = l >> 4, n16 = l & 15;
  int col = wv * 64 + q * 16 + n16;

  i32x8 wgt[16];
  #pragma unroll
  for (int ct = 0; ct < 4; ct++)
    #pragma unroll
    for (int kt = 0; kt < 4; kt++){
      int fidx = (wv * 4 + ct) * 4 + kt;
      uint4 wl = Wf4[(size_t)fidx * 64 + l];
      i32x8 w8 = {(int)wl.x, (int)wl.y, (int)wl.z, (int)wl.w, 0, 0, 0, 0};
      wgt[ct * 4 + kt] = w8;
    }

  toks[tid] = tokens[b * 512 + tid];
  if (tid < 64) ((u32*)gA)[tid] = 0;
  __syncthreads();

  const u16* xpc = xpV + col;                  // lane's column base
  u16 xraw = xpc[(size_t)toks[0] * 512];
  u32 greg = 0;

#define RNN_STEP(T, SRC, DST)                                                 \
  {                                                                           \
    int tn = toks[(T + 1) & 511];                                             \
    u16 xnext = xpc[(size_t)tn * 512];                                        \
    bool wr = toks[T] != 0;                                                   \
    i32x4 av0 = *(const i32x4*)(SRC + 0 * 64 + q * 16);                       \
    i32x4 av1 = *(const i32x4*)(SRC + 1 * 64 + q * 16);                       \
    i32x4 av2 = *(const i32x4*)(SRC + 2 * 64 + q * 16);                       \
    i32x4 av3 = *(const i32x4*)(SRC + 3 * 64 + q * 16);                       \
    i32x8 a80 = {av0[0], av0[1], av0[2], av0[3], 0, 0, 0, 0};                 \
    i32x8 a81 = {av1[0], av1[1], av1[2], av1[3], 0, 0, 0, 0};                 \
    i32x8 a82 = {av2[0], av2[1], av2[2], av2[3], 0, 0, 0, 0};                 \
    i32x8 a83 = {av3[0], av3[1], av3[2], av3[3], 0, 0, 0, 0};                 \
    f32x4 acc0 = {0.f,0.f,0.f,0.f}, acc1 = {0.f,0.f,0.f,0.f};                 \
    f32x4 acc2 = {0.f,0.f,0.f,0.f}, acc3 = {0.f,0.f,0.f,0.f};                 \
    __builtin_amdgcn_s_setprio(1);                                            \
    acc0 = __builtin_amdgcn_mfma_scale_f32_16x16x128_f8f6f4(a80, wgt[0],  acc0, 4, 4, 0, 127, 0, 127); \
    acc1 = __builtin_amdgcn_mfma_scale_f32_16x16x128_f8f6f4(a80, wgt[4],  acc1, 4, 4, 0, 127, 0, 127); \
    acc2 = __builtin_amdgcn_mfma_scale_f32_16x16x128_f8f6f4(a80, wgt[8],  acc2, 4, 4, 0, 127, 0, 127); \
    acc3 = __builtin_amdgcn_mfma_scale_f32_16x16x128_f8f6f4(a80, wgt[12], acc3, 4, 4, 0, 127, 0, 127); \
    acc0 = __builtin_amdgcn_mfma_scale_f32_16x16x128_f8f6f4(a81, wgt[1],  acc0, 4, 4, 0, 127, 0, 127); \
    acc1 = __builtin_amdgcn_mfma_scale_f32_16x16x128_f8f6f4(a81, wgt[5],  acc1, 4, 4, 0, 127, 0, 127); \
    acc2 = __builtin_amdgcn_mfma_scale_f32_16x16x128_f8f6f4(a81, wgt[9],  acc2, 4, 4, 0, 127, 0, 127); \
    acc3 = __builtin_amdgcn_mfma_scale_f32_16x16x128_f8f6f4(a81, wgt[13], acc3, 4, 4, 0, 127, 0, 127); \
    acc0 = __builtin_amdgcn_mfma_scale_f32_16x16x128_f8f6f4(a82, wgt[2],  acc0, 4, 4, 0, 127, 0, 127); \
    acc1 = __builtin_amdgcn_mfma_scale_f32_16x16x128_f8f6f4(a82, wgt[6],  acc1, 4, 4, 0, 127, 0, 127); \
    acc2 = __builtin_amdgcn_mfma_scale_f32_16x16x128_f8f6f4(a82, wgt[10], acc2, 4, 4, 0, 127, 0, 127); \
    acc3 = __builtin_amdgcn_mfma_scale_f32_16x16x128_f8f6f4(a82, wgt[14], acc3, 4, 4, 0, 127, 0, 127); \
    acc0 = __builtin_amdgcn_mfma_scale_f32_16x16x128_f8f6f4(a83, wgt[3],  acc0, 4, 4, 0, 127, 0, 127); \
    acc1 = __builtin_amdgcn_mfma_scale_f32_16x16x128_f8f6f4(a83, wgt[7],  acc1, 4, 4, 0, 127, 0, 127); \
    acc2 = __builtin_amdgcn_mfma_scale_f32_16x16x128_f8f6f4(a83, wgt[11], acc2, 4, 4, 0, 127, 0, 127); \
    acc3 = __builtin_amdgcn_mfma_scale_f32_16x16x128_f8f6f4(a83, wgt[15], acc3, 4, 4, 0, 127, 0, 127); \
    __builtin_amdgcn_s_setprio(0);                                            \
    float av = (q == 0) ? acc0[0] : (q == 1) ? acc1[0] : (q == 2) ? acc2[0] : acc3[0]; \
    float gn = fmaxf(fmaf(av, 1.0f / SW4, h2f(xraw)), 0.f);                   \
    u32 code;                                                                 \
    if (gn < 2.f) code = (u32)(int)rintf(gn * 2.f);                           \
    else if (gn < 4.f) code = 4u + (u32)(int)rintf(gn - 2.f);                 \
    else { u32 c = 6u + (u32)(int)rintf((gn - 4.f) * 0.5f); code = c > 7u ? 7u : c; } \
    u32 pc = (u32)__shfl_xor((int)code, 1);                                   \
    u32 byte = (n16 & 1) ? (pc | (code << 4)) : (code | (pc << 4));           \
    if (wr) greg = byte;                                                      \
    if ((l & 1) == 0) DST[col >> 1] = (unsigned char)greg;                    \
    xraw = xnext;                                                             \
  }

  #pragma unroll 1
  for (int t = 0; t < 512; t += 2){
    RNN_STEP(t, gA, gB);
    __syncthreads();
    RNN_STEP(t + 1, gB, gA);
    __syncthreads();
  }
#undef RNN_STEP

  if (tid < 256){
    u32 byte = gA[tid];
    float f0 = fp4val(byte & 15u) * (1.0f / SH4);
    float f1 = fp4val(byte >> 4) * (1.0f / SH4);
    hpack[b * 256 + tid] = packh2(f0, f1);
  }
}

// ---- per-pair barrier: 4 participant blocks on a dedicated counter ----
__device__ __forceinline__ void pairbar(u32* cnt){
  __threadfence();
  __syncthreads();
  if (threadIdx.x == 0){
    atomicAdd(cnt, 1u);
    while (__hip_atomic_load(cnt, __ATOMIC_ACQUIRE, __HIP_MEMORY_SCOPE_AGENT) < 4u)
      __builtin_amdgcn_s_sleep(1);
  }
  __syncthreads();
  __threadfence();
}

// ---- T: chained fc1->fc2->outz->norm. 128 blocks x 256 thr. ----
// block (nx = bid&3, bp = bid>>2): n-slice nx, batch pair (2bp, 2bp+1).
// Per-pair counters (4 blocks each): sync[bp], sync[32+bp], sync[64+bp].
__global__ __launch_bounds__(256) void k_tail2(const u32* __restrict__ hpack,
    const u32* __restrict__ W1p, const float* __restrict__ b1,
    const u32* __restrict__ W2p, const float* __restrict__ b2,
    const u32* __restrict__ Wop, const float* __restrict__ bo,
    u32* __restrict__ y1p, u32* __restrict__ y2p,
    float* __restrict__ zbuf, float* __restrict__ out, u32* __restrict__ sync){
  __shared__ u32 h0[512], h1[512];
  __shared__ float redm[4], reds[4];
  int bid = blockIdx.x, tid = threadIdx.x;
  int nx = bid & 3, bp = bid >> 2;
  int ba = bp * 2, bb = ba + 1;

  // phase 1: fc1
  {
    h0[tid] = hpack[ba * 256 + tid];
    h1[tid] = hpack[bb * 256 + tid];
    __syncthreads();
    int n = nx * 256 + tid;
    float a0 = 0.f, a1 = 0.f;
    #pragma unroll 8
    for (int p = 0; p < 256; p++){
      u32 w = W1p[p * FF_ + n];
      a0 = fdot2u(w, h0[p], a0);
      a1 = fdot2u(w, h1[p], a1);
    }
    float bbv = b1[n];
    float y0 = fmaxf(a0 + bbv, 0.f), y1 = fmaxf(a1 + bbv, 0.f);
    float o0 = __shfl_xor(y0, 1), o1 = __shfl_xor(y1, 1);
    if (!(tid & 1)){
      y1p[ba * 512 + (n >> 1)] = packh2(y0, o0);
      y1p[bb * 512 + (n >> 1)] = packh2(y1, o1);
    }
  }
  pairbar(sync + bp);
  __syncthreads();

  // phase 2: fc2
  {
    h0[tid] = y1p[ba * 512 + tid];       h1[tid] = y1p[bb * 512 + tid];
    h0[tid + 256] = y1p[ba * 512 + 256 + tid];
    h1[tid + 256] = y1p[bb * 512 + 256 + tid];
    __syncthreads();
    int n = nx * 256 + tid;
    float a0 = 0.f, a1 = 0.f;
    #pragma unroll 8
    for (int p = 0; p < 512; p++){
      u32 w = W2p[p * FF_ + n];
      a0 = fdot2u(w, h0[p], a0);
      a1 = fdot2u(w, h1[p], a1);
    }
    float bbv = b2[n];
    float y0 = fmaxf(a0 + bbv, 0.f), y1 = fmaxf(a1 + bbv, 0.f);
    float o0 = __shfl_xor(y0, 1), o1 = __shfl_xor(y1, 1);
    if (!(tid & 1)){
      y2p[ba * 512 + (n >> 1)] = packh2(y0, o0);
      y2p[bb * 512 + (n >> 1)] = packh2(y1, o1);
    }
  }
  pairbar(sync + 32 + bp);
  __syncthreads();

  // phase 3: outz (c-slice nx*250)
  {
    h0[tid] = y2p[ba * 512 + tid];       h1[tid] = y2p[bb * 512 + tid];
    h0[tid + 256] = y2p[ba * 512 + 256 + tid];
    h1[tid + 256] = y2p[bb * 512 + 256 + tid];
    __syncthreads();
    if (tid < 250){
      int n = nx * 250 + tid;
      float a0 = 0.f, a1 = 0.f;
      #pragma unroll 8
      for (int p = 0; p < 512; p++){
        u32 w = Wop[p * C_ + n];
        a0 = fdot2u(w, h0[p], a0);
        a1 = fdot2u(w, h1[p], a1);
      }
      float bbv = bo[n];
      zbuf[ba * C_ + n] = a0 + bbv;
      zbuf[bb * C_ + n] = a1 + bbv;
    }
  }
  pairbar(sync + 64 + bp);

  // phase 4: softmax normalize (nx<2 -> batch ba+nx)
  if (nx < 2){
    int b = ba + nx;
    float z0 = zbuf[b * C_ + tid];
    float z1 = zbuf[b * C_ + 256 + tid];
    float z2 = zbuf[b * C_ + 512 + tid];
    bool v3 = (768 + tid) < C_;
    float z3 = v3 ? zbuf[b * C_ + 768 + tid] : -1e30f;
    float mx = fmaxf(fmaxf(z0, z1), fmaxf(z2, z3));
    #pragma unroll
    for (int o = 1; o < 64; o <<= 1) mx = fmaxf(mx, __shfl_xor(mx, o));
    if ((tid & 63) == 0) redm[tid >> 6] = mx;
    __syncthreads();
    mx = fmaxf(fmaxf(redm[0], redm[1]), fmaxf(redm[2], redm[3]));
    float e0 = __expf(z0 - mx), e1 = __expf(z1 - mx), e2 = __expf(z2 - mx);
    float e3 = v3 ? __expf(z3 - mx) : 0.f;
    float s = e0 + e1 + e2 + e3;
    #pragma unroll
    for (int o = 1; o < 64; o <<= 1) s += __shfl_xor(s, o);
    if ((tid & 63) == 0) reds[tid >> 6] = s;
    __syncthreads();
    s = reds[0] + reds[1] + reds[2] + reds[3];
    float inv = 1.0f / s;
    out[b * C_ + tid] = e0 * inv;
    out[b * C_ + 256 + tid] = e1 * inv;
    out[b * C_ + 512 + tid] = e2 * inv;
    if (v3) out[b * C_ + 768 + tid] = e3 * inv;
  }
}

extern "C" void kernel_launch(void* const* d_in, const int* in_sizes, int n_in,
                              void* d_out, int out_size, void* d_ws, size_t ws_size,
                              hipStream_t stream) {
  const int*   tokens = (const int*)d_in[0];
  const float* emb    = (const float*)d_in[1];
  const float* Wx     = (const float*)d_in[2];
  const float* Wh     = (const float*)d_in[3];
  const float* brnn   = (const float*)d_in[4];
  const float* W1     = (const float*)d_in[5];
  const float* b1     = (const float*)d_in[6];
  const float* W2     = (const float*)d_in[7];
  const float* b2     = (const float*)d_in[8];
  const float* Wo     = (const float*)d_in[9];
  const float* bo     = (const float*)d_in[10];
  float* out = (float*)d_out;

  char* ws = (char*)d_ws;
  size_t off = 0;
  auto alloc = [&](size_t bytes) -> void* {
    void* p = ws + off;
    off += (bytes + 255) & ~(size_t)255;
    return p;
  };
  u16* WxT    = (u16*)alloc((size_t)512 * 512 * 2);
  u16* xpV    = (u16*)alloc((size_t)V_ * 512 * 2);
  uint4* Wf4  = (uint4*)alloc((size_t)128 * 64 * 16);
  u32* W1p    = (u32*)alloc((size_t)256 * 1024 * 4);
  u32* W2p    = (u32*)alloc((size_t)512 * 1024 * 4);
  u32* Wop    = (u32*)alloc((size_t)512 * 1000 * 4);
  u32* hpack  = (u32*)alloc((size_t)64 * 256 * 4);
  u32* y1p    = (u32*)alloc((size_t)64 * 512 * 4);
  u32* y2p    = (u32*)alloc((size_t)64 * 512 * 4);
  float* zbuf = (float*)alloc((size_t)64 * 1000 * 4);
  u32* sync   = (u32*)alloc(512);

  k_prep<<<dim3(96), dim3(256), 0, stream>>>(Wx, WxT, Wh, Wf4);
  k_gemm<<<dim3(3060), dim3(512), 0, stream>>>(emb, WxT, brnn, xpV,
                                               W1, W1p, W2, W2p, Wo, Wop, sync);
  k_rnn<<<dim3(64), dim3(512), 0, stream>>>(Wf4, xpV, tokens, hpack);
  k_tail2<<<dim3(128), dim3(256), 0, stream>>>(hpack, W1p, b1, W2p, b2, Wop, bo,
                                               y1p, y2p, zbuf, out, sync);
}

// Round 14
// 380.465 us; speedup vs baseline: 1.3250x; 1.1088x over previous
//
#include <hip/hip_runtime.h>
#include <stdint.h>

typedef _Float16 half2_t __attribute__((ext_vector_type(2)));
typedef short bf16x8 __attribute__((ext_vector_type(8)));
typedef float f32x4 __attribute__((ext_vector_type(4)));
typedef int i32x4 __attribute__((ext_vector_type(4)));
typedef int i32x8 __attribute__((ext_vector_type(8)));
typedef unsigned short u16;
typedef unsigned int u32;
typedef unsigned long long u64;

#define B_ 64
#define S_ 512
#define D_ 512
#define H_ 512
#define FF_ 1024
#define C_ 1000
#define V_ 32000

// scaling: W' = 128*Wh (fp4 e2m1), g = 256*h (fp4, >=0).
#define SW4 128.0f
#define SH4 256.0f

__device__ __forceinline__ u16 f2bf(float f){
  u32 u = __builtin_bit_cast(u32, f);
  u = (u + 0x7FFFu + ((u >> 16) & 1u)) >> 16;
  return (u16)u;
}
__device__ __forceinline__ u32 pkbf(float a, float b){
  return (u32)f2bf(a) | ((u32)f2bf(b) << 16);
}
__device__ __forceinline__ u32 packh2(float a, float b){
  u16 lo = __builtin_bit_cast(u16, (_Float16)a);
  u16 hi = __builtin_bit_cast(u16, (_Float16)b);
  return (u32)lo | ((u32)hi << 16);
}
__device__ __forceinline__ float fdot2u(u32 a, u32 b, float c){
  return __builtin_amdgcn_fdot2(__builtin_bit_cast(half2_t, a),
                                __builtin_bit_cast(half2_t, b), c, false);
}
__device__ __forceinline__ float h2f(u16 h){
  return (float)__builtin_bit_cast(_Float16, h);
}
__device__ __forceinline__ float fp4val(u32 c){
  int e = (c >> 1) & 3;
  float m = 1.0f + 0.5f * (float)(c & 1);
  return (e == 0) ? 0.5f * (float)(c & 1) : m * (float)(1 << (e - 1));
}

// ---- P: Wx transpose+cvt [0,64) | Wh fp4 fragments [64,96) ----
__global__ void k_prep(const float* __restrict__ Wx, u16* __restrict__ WxT,
                       const float* __restrict__ Wh, uint4* __restrict__ Wf4){
  __shared__ u16 t[64][65];
  int bid = blockIdx.x, tid = threadIdx.x;
  if (bid < 64){
    int bx = bid & 7, by = bid >> 3;
    int c = tid & 63, r0 = (tid >> 6) * 16;
    #pragma unroll
    for (int i = 0; i < 16; i++){
      int k = by * 64 + r0 + i, n = bx * 64 + c;
      t[r0 + i][c] = f2bf(Wx[k * 512 + n]);
    }
    __syncthreads();
    #pragma unroll
    for (int i = 0; i < 16; i++){
      int n = bx * 64 + r0 + i, k = by * 64 + c;
      WxT[n * 512 + k] = t[c][r0 + i];
    }
  } else {
    int g = (bid - 64) * 256 + tid;            // 8192
    int fidx = g >> 6, l = g & 63;
    int wv = fidx >> 4, ct = (fidx >> 2) & 3, kt = fidx & 3;
    int q = l >> 4, n = wv * 64 + ct * 16 + (l & 15);
    int k0 = kt * 128 + q * 32;
    u32 d[4] = {0u, 0u, 0u, 0u};
    #pragma unroll
    for (int j = 0; j < 32; j++){
      float w = Wh[(size_t)(k0 + j) * 512 + n] * SW4;
      float aw = fabsf(w);
      u32 s = (w < 0.f) ? 8u : 0u;
      u32 c;
      if (aw < 2.f) c = (u32)(int)rintf(aw * 2.f);
      else if (aw < 4.f) c = 4u + (u32)(int)rintf(aw - 2.f);
      else { c = 6u + (u32)(int)rintf((aw - 4.f) * 0.5f); if (c > 7u) c = 7u; }
      d[j >> 3] |= (c | s) << (4 * (j & 7));
    }
    uint4 o; o.x = d[0]; o.y = d[1]; o.z = d[2]; o.w = d[3];
    Wf4[(size_t)fidx * 64 + l] = o;
  }
}

// ---- G: vocab GEMM [0,500) + weight packs [500,3060) ----
__global__ __launch_bounds__(512) void k_gemm(const float* __restrict__ emb,
                                              const u16* __restrict__ WxT,
                                              const float* __restrict__ bias,
                                              u16* __restrict__ xpV,
                                              const float* __restrict__ W1, u32* __restrict__ W1p,
                                              const float* __restrict__ W2, u32* __restrict__ W2p,
                                              const float* __restrict__ Wo, u32* __restrict__ Wop){
  __shared__ __align__(16) u16 As[64 * 40];
  int bid = blockIdx.x, tid = threadIdx.x;
  if (bid >= 500){
    if (bid < 1012){
      int i = (bid - 500) * 512 + tid;         // 262144 = 256p x 1024n
      int p = i >> 10, n = i & 1023;
      W1p[p * FF_ + n] = packh2(W1[(2 * p) * FF_ + n], W1[(2 * p + 1) * FF_ + n]);
    } else if (bid < 2036){
      int i = (bid - 1012) * 512 + tid;        // 524288 = 512p x 1024n
      int p = i >> 10, n = i & 1023;
      W2p[p * FF_ + n] = packh2(W2[(2 * p) * FF_ + n], W2[(2 * p + 1) * FF_ + n]);
    } else {
      int i = (bid - 2036) * 512 + tid;        // 512p x 1024 (n<1000 valid)
      int p = i >> 10, n = i & 1023;
      if (n < C_)
        Wop[p * C_ + n] = packh2(Wo[(2 * p) * C_ + n], Wo[(2 * p + 1) * C_ + n]);
    }
    return;
  }
  int m0 = bid * 64;
  int w = tid >> 6, l = tid & 63, kg = l >> 4, r16 = l & 15;
  const u16* bptr[4];
  #pragma unroll
  for (int ni = 0; ni < 4; ni++)
    bptr[ni] = WxT + (size_t)(w * 64 + ni * 16 + r16) * 512 + kg * 8;
  f32x4 acc[4][4];
  #pragma unroll
  for (int mi = 0; mi < 4; mi++)
    #pragma unroll
    for (int ni = 0; ni < 4; ni++) acc[mi][ni] = (f32x4){0.f, 0.f, 0.f, 0.f};
  int srow = tid >> 3, sk = (tid & 7) * 4;
  const float* ebase = emb + (size_t)(m0 + srow) * 512 + sk;
  float4 f = *(const float4*)ebase;            // kt = 0
  for (int kt = 0; kt < 16; kt++){
    u32 lo = pkbf(f.x, f.y), hi = pkbf(f.z, f.w);
    float4 fn;
    if (kt < 15) fn = *(const float4*)(ebase + (kt + 1) * 32);   // prefetch
    __syncthreads();
    uint2 st; st.x = lo; st.y = hi;
    *(uint2*)(As + srow * 40 + sk) = st;
    __syncthreads();
    bf16x8 bfr[4], af[4];
    #pragma unroll
    for (int ni = 0; ni < 4; ni++)
      bfr[ni] = *(const bf16x8*)(bptr[ni] + kt * 32);
    #pragma unroll
    for (int mi = 0; mi < 4; mi++)
      af[mi] = *(const bf16x8*)(As + (mi * 16 + r16) * 40 + kg * 8);
    #pragma unroll
    for (int mi = 0; mi < 4; mi++)
      #pragma unroll
      for (int ni = 0; ni < 4; ni++)
        acc[mi][ni] = __builtin_amdgcn_mfma_f32_16x16x32_bf16(af[mi], bfr[ni], acc[mi][ni], 0, 0, 0);
    f = fn;
  }
  #pragma unroll
  for (int ni = 0; ni < 4; ni++){
    int col = w * 64 + ni * 16 + r16;
    float bb = bias[col];
    #pragma unroll
    for (int mi = 0; mi < 4; mi++){
      int mb = m0 + mi * 16 + kg * 4;
      #pragma unroll
      for (int r = 0; r < 4; r++){
        float v = (acc[mi][ni][r] + bb) * SH4;
        xpV[(size_t)(mb + r) * 512 + col] = __builtin_bit_cast(u16, (_Float16)v);
      }
    }
  }
}

// ---- R: 512-step RNN scan (R11 core) + fused per-batch MLP tail. ----
// 64 blocks x 512 thr. Scan: MX-fp4 MFMA, 254 us proven. Tail: batch-local
// fc1->fc2->outz->softmax, no cross-block sync, ~5MB weight ingest per CU.
__global__ __launch_bounds__(512, 2) void k_rnnt(
    const uint4* __restrict__ Wf4, const u16* __restrict__ xpV,
    const int* __restrict__ tokens,
    const u32* __restrict__ W1p, const float* __restrict__ b1,
    const u32* __restrict__ W2p, const float* __restrict__ b2,
    const u32* __restrict__ Wop, const float* __restrict__ bo,
    float* __restrict__ out){
  __shared__ __align__(16) unsigned char gA[256];
  __shared__ __align__(16) unsigned char gB[256];
  __shared__ int toks[512];
  __shared__ __align__(16) u32 bufA[512];
  __shared__ __align__(16) u32 bufB[512];
  __shared__ float redm[8], reds[8];
  int b = blockIdx.x, tid = threadIdx.x;
  int wv = tid >> 6, l = tid & 63, q = l >> 4, n16 = l & 15;
  int col = wv * 64 + q * 16 + n16;

  i32x8 wgt[16];
  #pragma unroll
  for (int ct = 0; ct < 4; ct++)
    #pragma unroll
    for (int kt = 0; kt < 4; kt++){
      int fidx = (wv * 4 + ct) * 4 + kt;
      uint4 wl = Wf4[(size_t)fidx * 64 + l];
      i32x8 w8 = {(int)wl.x, (int)wl.y, (int)wl.z, (int)wl.w, 0, 0, 0, 0};
      wgt[ct * 4 + kt] = w8;
    }

  toks[tid] = tokens[b * 512 + tid];
  if (tid < 64) ((u32*)gA)[tid] = 0;
  __syncthreads();

  const u16* xpc = xpV + col;                  // lane's column base
  u16 xraw = xpc[(size_t)toks[0] * 512];
  u32 greg = 0;

#define RNN_STEP(T, SRC, DST)                                                 \
  {                                                                           \
    int tn = toks[(T + 1) & 511];                                             \
    u16 xnext = xpc[(size_t)tn * 512];                                        \
    bool wr = toks[T] != 0;                                                   \
    i32x4 av0 = *(const i32x4*)(SRC + 0 * 64 + q * 16);                       \
    i32x4 av1 = *(const i32x4*)(SRC + 1 * 64 + q * 16);                       \
    i32x4 av2 = *(const i32x4*)(SRC + 2 * 64 + q * 16);                       \
    i32x4 av3 = *(const i32x4*)(SRC + 3 * 64 + q * 16);                       \
    i32x8 a80 = {av0[0], av0[1], av0[2], av0[3], 0, 0, 0, 0};                 \
    i32x8 a81 = {av1[0], av1[1], av1[2], av1[3], 0, 0, 0, 0};                 \
    i32x8 a82 = {av2[0], av2[1], av2[2], av2[3], 0, 0, 0, 0};                 \
    i32x8 a83 = {av3[0], av3[1], av3[2], av3[3], 0, 0, 0, 0};                 \
    f32x4 acc0 = {0.f,0.f,0.f,0.f}, acc1 = {0.f,0.f,0.f,0.f};                 \
    f32x4 acc2 = {0.f,0.f,0.f,0.f}, acc3 = {0.f,0.f,0.f,0.f};                 \
    __builtin_amdgcn_s_setprio(1);                                            \
    acc0 = __builtin_amdgcn_mfma_scale_f32_16x16x128_f8f6f4(a80, wgt[0],  acc0, 4, 4, 0, 127, 0, 127); \
    acc1 = __builtin_amdgcn_mfma_scale_f32_16x16x128_f8f6f4(a80, wgt[4],  acc1, 4, 4, 0, 127, 0, 127); \
    acc2 = __builtin_amdgcn_mfma_scale_f32_16x16x128_f8f6f4(a80, wgt[8],  acc2, 4, 4, 0, 127, 0, 127); \
    acc3 = __builtin_amdgcn_mfma_scale_f32_16x16x128_f8f6f4(a80, wgt[12], acc3, 4, 4, 0, 127, 0, 127); \
    acc0 = __builtin_amdgcn_mfma_scale_f32_16x16x128_f8f6f4(a81, wgt[1],  acc0, 4, 4, 0, 127, 0, 127); \
    acc1 = __builtin_amdgcn_mfma_scale_f32_16x16x128_f8f6f4(a81, wgt[5],  acc1, 4, 4, 0, 127, 0, 127); \
    acc2 = __builtin_amdgcn_mfma_scale_f32_16x16x128_f8f6f4(a81, wgt[9],  acc2, 4, 4, 0, 127, 0, 127); \
    acc3 = __builtin_amdgcn_mfma_scale_f32_16x16x128_f8f6f4(a81, wgt[13], acc3, 4, 4, 0, 127, 0, 127); \
    acc0 = __builtin_amdgcn_mfma_scale_f32_16x16x128_f8f6f4(a82, wgt[2],  acc0, 4, 4, 0, 127, 0, 127); \
    acc1 = __builtin_amdgcn_mfma_scale_f32_16x16x128_f8f6f4(a82, wgt[6],  acc1, 4, 4, 0, 127, 0, 127); \
    acc2 = __builtin_amdgcn_mfma_scale_f32_16x16x128_f8f6f4(a82, wgt[10], acc2, 4, 4, 0, 127, 0, 127); \
    acc3 = __builtin_amdgcn_mfma_scale_f32_16x16x128_f8f6f4(a82, wgt[14], acc3, 4, 4, 0, 127, 0, 127); \
    acc0 = __builtin_amdgcn_mfma_scale_f32_16x16x128_f8f6f4(a83, wgt[3],  acc0, 4, 4, 0, 127, 0, 127); \
    acc1 = __builtin_amdgcn_mfma_scale_f32_16x16x128_f8f6f4(a83, wgt[7],  acc1, 4, 4, 0, 127, 0, 127); \
    acc2 = __builtin_amdgcn_mfma_scale_f32_16x16x128_f8f6f4(a83, wgt[11], acc2, 4, 4, 0, 127, 0, 127); \
    acc3 = __builtin_amdgcn_mfma_scale_f32_16x16x128_f8f6f4(a83, wgt[15], acc3, 4, 4, 0, 127, 0, 127); \
    __builtin_amdgcn_s_setprio(0);                                            \
    float av = (q == 0) ? acc0[0] : (q == 1) ? acc1[0] : (q == 2) ? acc2[0] : acc3[0]; \
    float gn = fmaxf(fmaf(av, 1.0f / SW4, h2f(xraw)), 0.f);                   \
    u32 code;                                                                 \
    if (gn < 2.f) code = (u32)(int)rintf(gn * 2.f);                           \
    else if (gn < 4.f) code = 4u + (u32)(int)rintf(gn - 2.f);                 \
    else { u32 c = 6u + (u32)(int)rintf((gn - 4.f) * 0.5f); code = c > 7u ? 7u : c; } \
    u32 pc = (u32)__shfl_xor((int)code, 1);                                   \
    u32 byte = (n16 & 1) ? (pc | (code << 4)) : (code | (pc << 4));           \
    if (wr) greg = byte;                                                      \
    if ((l & 1) == 0) DST[col >> 1] = (unsigned char)greg;                    \
    xraw = xnext;                                                             \
  }

  #pragma unroll 1
  for (int t = 0; t < 512; t += 2){
    RNN_STEP(t, gA, gB);
    __syncthreads();
    RNN_STEP(t + 1, gB, gA);
    __syncthreads();
  }
#undef RNN_STEP

  // ---- fused per-batch tail: h -> fc1 -> fc2 -> logits -> softmax ----
  // decode final h (fp4 in gA) into half2 pairs: bufB[0..255]
  if (tid < 256){
    u32 byte = gA[tid];
    float f0 = fp4val(byte & 15u) * (1.0f / SH4);
    float f1 = fp4val(byte >> 4) * (1.0f / SH4);
    bufB[tid] = packh2(f0, f1);
  }
  __syncthreads();

  // fc1: outs n = tid, tid+512 ; K=256 pairs from bufB -> bufA[512]
  {
    float a0 = 0.f, a1 = 0.f;
    #pragma unroll 8
    for (int p = 0; p < 256; p++){
      u32 h = bufB[p];
      a0 = fdot2u(W1p[p * FF_ + tid], h, a0);
      a1 = fdot2u(W1p[p * FF_ + tid + 512], h, a1);
    }
    float y0 = fmaxf(a0 + b1[tid], 0.f);
    float y1 = fmaxf(a1 + b1[tid + 512], 0.f);
    float o0 = __shfl_xor(y0, 1), o1 = __shfl_xor(y1, 1);
    if (!(tid & 1)){
      bufA[tid >> 1] = packh2(y0, o0);
      bufA[256 + (tid >> 1)] = packh2(y1, o1);
    }
  }
  __syncthreads();

  // fc2: outs n = tid, tid+512 ; K=512 pairs from bufA -> bufB[512]
  {
    float a0 = 0.f, a1 = 0.f;
    #pragma unroll 8
    for (int p = 0; p < 512; p++){
      u32 h = bufA[p];
      a0 = fdot2u(W2p[p * FF_ + tid], h, a0);
      a1 = fdot2u(W2p[p * FF_ + tid + 512], h, a1);
    }
    float y0 = fmaxf(a0 + b2[tid], 0.f);
    float y1 = fmaxf(a1 + b2[tid + 512], 0.f);
    float o0 = __shfl_xor(y0, 1), o1 = __shfl_xor(y1, 1);
    if (!(tid & 1)){
      bufB[tid >> 1] = packh2(y0, o0);
      bufB[256 + (tid >> 1)] = packh2(y1, o1);
    }
  }
  __syncthreads();

  // outz + softmax: outs n0 = tid, n1 = tid+512 (valid while < 1000)
  {
    int n0 = tid, n1 = tid + 512;
    bool v1 = n1 < C_;
    int n1c = v1 ? n1 : 0;
    float z0 = 0.f, z1 = 0.f;
    #pragma unroll 8
    for (int p = 0; p < 512; p++){
      u32 y = bufB[p];
      z0 = fdot2u(Wop[p * C_ + n0], y, z0);
      z1 = fdot2u(Wop[p * C_ + n1c], y, z1);
    }
    z0 += bo[n0];
    z1 += bo[n1c];
    float mx = fmaxf(z0, v1 ? z1 : -1e30f);
    #pragma unroll
    for (int o = 1; o < 64; o <<= 1) mx = fmaxf(mx, __shfl_xor(mx, o));
    if ((tid & 63) == 0) redm[wv] = mx;
    __syncthreads();
    mx = redm[0];
    #pragma unroll
    for (int i = 1; i < 8; i++) mx = fmaxf(mx, redm[i]);
    float e0 = __expf(z0 - mx);
    float e1 = v1 ? __expf(z1 - mx) : 0.f;
    float s = e0 + e1;
    #pragma unroll
    for (int o = 1; o < 64; o <<= 1) s += __shfl_xor(s, o);
    if ((tid & 63) == 0) reds[wv] = s;
    __syncthreads();
    s = 0.f;
    #pragma unroll
    for (int i = 0; i < 8; i++) s += reds[i];
    float inv = 1.0f / s;
    out[(size_t)b * C_ + n0] = e0 * inv;
    if (v1) out[(size_t)b * C_ + n1] = e1 * inv;
  }
}

extern "C" void kernel_launch(void* const* d_in, const int* in_sizes, int n_in,
                              void* d_out, int out_size, void* d_ws, size_t ws_size,
                              hipStream_t stream) {
  const int*   tokens = (const int*)d_in[0];
  const float* emb    = (const float*)d_in[1];
  const float* Wx     = (const float*)d_in[2];
  const float* Wh     = (const float*)d_in[3];
  const float* brnn   = (const float*)d_in[4];
  const float* W1     = (const float*)d_in[5];
  const float* b1     = (const float*)d_in[6];
  const float* W2     = (const float*)d_in[7];
  const float* b2     = (const float*)d_in[8];
  const float* Wo     = (const float*)d_in[9];
  const float* bo     = (const float*)d_in[10];
  float* out = (float*)d_out;

  char* ws = (char*)d_ws;
  size_t off = 0;
  auto alloc = [&](size_t bytes) -> void* {
    void* p = ws + off;
    off += (bytes + 255) & ~(size_t)255;
    return p;
  };
  u16* WxT    = (u16*)alloc((size_t)512 * 512 * 2);
  u16* xpV    = (u16*)alloc((size_t)V_ * 512 * 2);
  uint4* Wf4  = (uint4*)alloc((size_t)128 * 64 * 16);
  u32* W1p    = (u32*)alloc((size_t)256 * 1024 * 4);
  u32* W2p    = (u32*)alloc((size_t)512 * 1024 * 4);
  u32* Wop    = (u32*)alloc((size_t)512 * 1000 * 4);

  k_prep<<<dim3(96), dim3(256), 0, stream>>>(Wx, WxT, Wh, Wf4);
  k_gemm<<<dim3(3060), dim3(512), 0, stream>>>(emb, WxT, brnn, xpV,
                                               W1, W1p, W2, W2p, Wo, Wop);
  k_rnnt<<<dim3(64), dim3(512), 0, stream>>>(Wf4, xpV, tokens,
                                             W1p, b1, W2p, b2, Wop, bo, out);
}